// Round 8
// baseline (349.358 us; speedup 1.0000x reference)
//
#include <hip/hip_runtime.h>
#include <math.h>

#define B_ 4
#define C_ 512
#define D_ 128
#define N_ 4096

typedef short s4v __attribute__((ext_vector_type(4)));
typedef short s8v __attribute__((ext_vector_type(8)));
typedef float f4v __attribute__((ext_vector_type(4)));

__device__ __forceinline__ unsigned short f2bf(float x) {
    union { float f; unsigned u; } v; v.f = x;
    unsigned r = v.u + 0x7FFF + ((v.u >> 16) & 1);   // RNE
    return (unsigned short)(r >> 16);
}
__device__ __forceinline__ float bf2f(unsigned short h) {
    union { unsigned u; float f; } v; v.u = ((unsigned)h) << 16; return v.f;
}

// ---------------------------------------------------------------------------
// W/bias pre-convert: Wb rows [0:64]=Wq | [64:128]=Wk | [128:640]=Wv |
// [640:704]=Wdq | [704:768]=Wdk (bf16, row-major 512). biasb same order f32.
// ---------------------------------------------------------------------------
__global__ __launch_bounds__(256) void cvt_w_kernel(
    const float* __restrict__ Wq,  const float* __restrict__ bq,
    const float* __restrict__ Wk,  const float* __restrict__ bk,
    const float* __restrict__ Wdq, const float* __restrict__ bdq,
    const float* __restrict__ Wdk, const float* __restrict__ bdk,
    const float* __restrict__ Wv,  const float* __restrict__ bv,
    unsigned short* __restrict__ Wb, float* __restrict__ biasb)
{
    int t = blockIdx.x * 256 + threadIdx.x;        // 192 blocks
    int e0 = t * 8;
    int row = e0 >> 9, c = e0 & 511;
    const float* src; int r0;
    if (row < 64)       { src = Wq;  r0 = row; }
    else if (row < 128) { src = Wk;  r0 = row - 64; }
    else if (row < 640) { src = Wv;  r0 = row - 128; }
    else if (row < 704) { src = Wdq; r0 = row - 640; }
    else                { src = Wdk; r0 = row - 704; }
    const float* p = src + (size_t)r0 * 512 + c;
    s8v o;
    #pragma unroll
    for (int u = 0; u < 8; ++u) ((unsigned short*)&o)[u] = f2bf(p[u]);
    *(s8v*)&Wb[e0] = o;
    if (blockIdx.x == 0) {
        #pragma unroll
        for (int s = 0; s < 3; ++s) {
            int o2 = threadIdx.x + 256 * s;
            float v;
            if (o2 < 64)       v = bq[o2];
            else if (o2 < 128) v = bk[o2 - 64];
            else if (o2 < 640) v = bv[o2 - 128];
            else if (o2 < 704) v = bdq[o2 - 640];
            else               v = bdk[o2 - 704];
            biasb[o2] = v;
        }
    }
}

// ---------------------------------------------------------------------------
// Transpose-convert: x[st][b][c][i] fp32 -> Xt[st][b][i][c] bf16.
// Grid (64 iT x 8 cT, 4 b, 2 st) = 4096 blocks; 64x64 tile via LDS.
// ---------------------------------------------------------------------------
__global__ __launch_bounds__(256) void xpose_kernel(
    const float* __restrict__ x_rgb, const float* __restrict__ x_dep,
    unsigned short* __restrict__ Xt)
{
    __shared__ __align__(16) unsigned short Ls[64 * 72];
    const int cT = blockIdx.x & 7, iT = blockIdx.x >> 3;
    const int b = blockIdx.y, st = blockIdx.z;
    const int t = threadIdx.x;
    const float* Xb = (st ? x_dep : x_rgb) + (size_t)b * C_ * N_;

    const int c4 = t >> 4, i4 = t & 15;          // 4c x 4i block per thread
    {
        const float* xp = Xb + (size_t)(cT * 64 + c4 * 4) * N_ + iT * 64 + i4 * 4;
        float4 r0 = *(const float4*)(xp);
        float4 r1 = *(const float4*)(xp + N_);
        float4 r2 = *(const float4*)(xp + 2 * N_);
        float4 r3 = *(const float4*)(xp + 3 * N_);
        s4v p0 = { (short)f2bf(r0.x), (short)f2bf(r1.x), (short)f2bf(r2.x), (short)f2bf(r3.x) };
        s4v p1 = { (short)f2bf(r0.y), (short)f2bf(r1.y), (short)f2bf(r2.y), (short)f2bf(r3.y) };
        s4v p2 = { (short)f2bf(r0.z), (short)f2bf(r1.z), (short)f2bf(r2.z), (short)f2bf(r3.z) };
        s4v p3 = { (short)f2bf(r0.w), (short)f2bf(r1.w), (short)f2bf(r2.w), (short)f2bf(r3.w) };
        *(s4v*)&Ls[(i4 * 4 + 0) * 72 + c4 * 4] = p0;
        *(s4v*)&Ls[(i4 * 4 + 1) * 72 + c4 * 4] = p1;
        *(s4v*)&Ls[(i4 * 4 + 2) * 72 + c4 * 4] = p2;
        *(s4v*)&Ls[(i4 * 4 + 3) * 72 + c4 * 4] = p3;
    }
    __syncthreads();
    unsigned short* dst = Xt + ((size_t)(st * 4 + b) * N_ + iT * 64) * 512 + cT * 64;
    #pragma unroll
    for (int s = 0; s < 2; ++s) {
        int lin = t + 256 * s;
        int row = lin >> 3, g = lin & 7;
        *(s8v*)&dst[(size_t)row * 512 + g * 8] = *(const s8v*)&Ls[row * 72 + g * 8];
    }
}

// ---------------------------------------------------------------------------
// Projection GEMM (m97-style, R12 structure — UNCHANGED).
// ---------------------------------------------------------------------------
__global__ __launch_bounds__(256) void gemm_kernel(
    const unsigned short* __restrict__ Wb, const float* __restrict__ biasb,
    const unsigned short* __restrict__ Xt,
    unsigned short* __restrict__ Q, unsigned short* __restrict__ K,
    unsigned short* __restrict__ V)
{
    __shared__ __align__(16) unsigned short Ws[128 * 64];
    __shared__ __align__(16) unsigned short Xs[128 * 64];
    const int b  = blockIdx.x >> 5;
    const int i0 = (blockIdx.x & 31) * 128;
    const int by = blockIdx.y;
    const int mbase = by * 128;
    const int st = (by == 5);
    const int t = threadIdx.x, w = t >> 6;
    const int lane = t & 63, col = lane & 15, quad = lane >> 4;
    const int mh = (w & 1) * 64, nh = (w >> 1) * 64;

    const unsigned short* Wg = Wb + (size_t)mbase * 512;
    const unsigned short* Xg = Xt + ((size_t)(st * 4 + b) * N_ + i0) * 512;

    f4v acc[4][4];
    #pragma unroll
    for (int mt = 0; mt < 4; ++mt)
        #pragma unroll
        for (int nt = 0; nt < 4; ++nt) acc[mt][nt] = (f4v){0.f, 0.f, 0.f, 0.f};

    for (int kc = 0; kc < 8; ++kc) {
        const int k0 = kc * 64;
        s8v wt[4], xt[4];
        #pragma unroll
        for (int s = 0; s < 4; ++s) {
            int lin = t + 256 * s;
            int row = lin >> 3, g = lin & 7;
            wt[s] = *(const s8v*)&Wg[(size_t)row * 512 + k0 + g * 8];
            xt[s] = *(const s8v*)&Xg[(size_t)row * 512 + k0 + g * 8];
        }
        __syncthreads();                       // prior iter's frag reads done
        #pragma unroll
        for (int s = 0; s < 4; ++s) {
            int lin = t + 256 * s;
            int row = lin >> 3, g = lin & 7;
            int soff = row * 64 + ((g ^ (row & 7)) * 8);
            *(s8v*)&Ws[soff] = wt[s];
            *(s8v*)&Xs[soff] = xt[s];
        }
        __syncthreads();                       // tile staged
        #pragma unroll
        for (int kk = 0; kk < 2; ++kk) {
            const int gq = kk * 4 + quad;
            s8v af[4], bf[4];
            #pragma unroll
            for (int mt = 0; mt < 4; ++mt) {
                int r = mh + mt * 16 + col;
                af[mt] = *(const s8v*)&Ws[r * 64 + ((gq ^ (r & 7)) * 8)];
            }
            #pragma unroll
            for (int nt = 0; nt < 4; ++nt) {
                int r = nh + nt * 16 + col;
                bf[nt] = *(const s8v*)&Xs[r * 64 + ((gq ^ (r & 7)) * 8)];
            }
            #pragma unroll
            for (int nt = 0; nt < 4; ++nt)
                #pragma unroll
                for (int mt = 0; mt < 4; ++mt)
                    acc[mt][nt] = __builtin_amdgcn_mfma_f32_16x16x32_bf16(
                        af[mt], bf[nt], acc[mt][nt], 0, 0, 0);
        }
    }

    // ---- epilogue ----
    const int mlo0 = mbase + mh;               // wave-uniform
    #pragma unroll
    for (int mt = 0; mt < 4; ++mt) {
        const int mlo = mlo0 + mt * 16;
        f4v bi = *(const f4v*)&biasb[mlo + quad * 4];
        if (mlo < 128 || mlo >= 640) {         // Q/K rows
            unsigned short* dst; int dbase;
            if (mlo < 64)       { dst = Q; dbase = mlo; }
            else if (mlo < 128) { dst = K; dbase = mlo - 64; }
            else if (mlo < 704) { dst = Q; dbase = 64 + (mlo - 640); }
            else                { dst = K; dbase = 64 + (mlo - 704); }
            #pragma unroll
            for (int nt = 0; nt < 4; ++nt) {
                int i = i0 + nh + nt * 16 + col;
                s4v pk = { (short)f2bf(acc[mt][nt][0] + bi[0]),
                           (short)f2bf(acc[mt][nt][1] + bi[1]),
                           (short)f2bf(acc[mt][nt][2] + bi[2]),
                           (short)f2bf(acc[mt][nt][3] + bi[3]) };
                *(s4v*)&dst[((size_t)b * N_ + i) * D_ + dbase + quad * 4] = pk;
            }
        } else {                               // V rows
            int c0 = mlo - 128 + quad * 4;
            #pragma unroll
            for (int nt = 0; nt < 4; ++nt) {
                int i = i0 + nh + nt * 16 + col;
                #pragma unroll
                for (int r = 0; r < 4; ++r)
                    V[((size_t)b * C_ + c0 + r) * N_ + i] =
                        f2bf(acc[mt][nt][r] + bi[r]);
            }
        }
    }
}

// ---------------------------------------------------------------------------
// MFMA flash attention — R13 c-split-4 restructure.
// The binding constraint through R12 was registers: accO[4][8]=128 AGPR +
// 124 VGPR => 2 waves/SIMD (m69 cliff at 256). Split the c-dimension 4-way:
// each block computes 64i x 128c (grid 2048 = 4 cq per (b,jh,it)).
//  * Wave = 64i x 32c -> accO[4][2] = 32 AGPR; vt 8->2; Vs 32KB->8KB.
//    Target total regs ~116 <= 128 => 4 waves/SIMD (2x occupancy), enforced
//    by __launch_bounds__(256,4).
//  * QK^T + softmax duplicated across the 4 cq blocks (QK is 8 of 40
//    MFMA/iter; per-SIMD MFMA cycles DROP 388->310 despite duplication).
//  * Proven skeleton kept: 3 lgkm-only barriers, no vmcnt(0) in loop, kt
//    oldest-first, Vs write after QK+softmax, XCD group swizzle (id&7 =
//    (b,jh)), setprio around PV.
// Hazards: identical interval structure to R9/R10 (single Ks/Ps/Vs).
// LDS: Ks 8704 | Ps 5120 | Vs[128*32] 8192 | lred 512 = 22528 B.
// O layout: per (jh,b,it): 16 cblk (=cq*4+w) x 2048; elem (ct*4+rt)*256
// + lane*4 maps to O[i=rt*16+qd*4+r][c=cblk*32+ct*16+col].
// ---------------------------------------------------------------------------
__global__ __launch_bounds__(256, 4) void attn_kernel(
    const unsigned short* __restrict__ Q, const unsigned short* __restrict__ K,
    const unsigned short* __restrict__ V,
    unsigned short* __restrict__ O_ws, float* __restrict__ l_ws)
{
    __shared__ __align__(16) unsigned short Ks[32 * 136];
    __shared__ __align__(16) unsigned short Ps[64 * 40];
    __shared__ __align__(16) unsigned short Vs[128 * 32];
    __shared__ float lred[2][64];

    const int id  = blockIdx.x;             // 2048 flat
    const int grp = id & 7;                 // XCD-affine group
    const int b   = grp & 3;
    const int jh  = grp >> 2;
    const int r_  = id >> 3;                // [0,256)
    const int cq  = r_ & 3;                 // c-quarter
    const int it  = r_ >> 2;                // i-tile 0..63
    const int i0  = it * 64;
    const int jb  = jh * 2048;
    const int t = threadIdx.x, w = t >> 6;
    const int lane = t & 63, col = lane & 15, quad = lane >> 4;
    const int ih = w & 1, jq = w >> 1;

    const unsigned short* Kg = K + (size_t)b * N_ * D_;
    const unsigned short* Vg = V + ((size_t)b * C_ + cq * 128) * N_;

    s8v qf[2][4];
    #pragma unroll
    for (int ig = 0; ig < 2; ++ig) {
        const unsigned short* qr =
            Q + ((size_t)b * N_ + i0 + ih * 32 + ig * 16 + col) * D_ + quad * 8;
        #pragma unroll
        for (int kk = 0; kk < 4; ++kk) qf[ig][kk] = *(const s8v*)(qr + kk * 32);
    }

    f4v accO[4][2];
    #pragma unroll
    for (int rt = 0; rt < 4; ++rt)
        #pragma unroll
        for (int ct = 0; ct < 2; ++ct) accO[rt][ct] = (f4v){0.f, 0.f, 0.f, 0.f};
    float lsum[2] = {0.f, 0.f};

    for (int tt = 0; tt < 64; ++tt) {
        const int j0 = jb + tt * 32;
        // issue loads: kt FIRST (oldest -> Ks write waits only kt)
        s8v kt[2], vt[2];
        #pragma unroll
        for (int s = 0; s < 2; ++s) {
            int gi = t + 256 * s;
            kt[s] = *(const s8v*)&Kg[(size_t)(j0 + (gi >> 4)) * D_ + (gi & 15) * 8];
        }
        #pragma unroll
        for (int s = 0; s < 2; ++s) {
            int gi = t + 256 * s;
            vt[s] = *(const s8v*)&Vg[(size_t)(gi >> 2) * N_ + j0 + (gi & 3) * 8];
        }
        // B1: prior iter's Vs/Ps/Ks reads complete
        asm volatile("s_waitcnt lgkmcnt(0)" ::: "memory");
        __builtin_amdgcn_s_barrier();
        // stage K tile (counted vmcnt waits kt only; vt stays in flight)
        #pragma unroll
        for (int s = 0; s < 2; ++s) {
            int gi = t + 256 * s;
            *(s8v*)&Ks[(gi >> 4) * 136 + (gi & 15) * 8] = kt[s];
        }
        // B2: K tile staged
        asm volatile("s_waitcnt lgkmcnt(0)" ::: "memory");
        __builtin_amdgcn_s_barrier();
        // QK^T
        f4v s0 = (f4v){0.f, 0.f, 0.f, 0.f};
        f4v s1 = (f4v){0.f, 0.f, 0.f, 0.f};
        #pragma unroll
        for (int kk = 0; kk < 4; ++kk) {
            s8v kf = *(const s8v*)&Ks[(jq * 16 + col) * 136 + kk * 32 + quad * 8];
            s0 = __builtin_amdgcn_mfma_f32_16x16x32_bf16(kf, qf[0][kk], s0, 0, 0, 0);
            s1 = __builtin_amdgcn_mfma_f32_16x16x32_bf16(kf, qf[1][kk], s1, 0, 0, 0);
        }
        // softmax partials + pack P
        #pragma unroll
        for (int ig = 0; ig < 2; ++ig) {
            f4v sv = ig ? s1 : s0;
            s4v p; float ls = 0.f;
            #pragma unroll
            for (int r = 0; r < 4; ++r) {
                float e = __expf(sv[r]);
                ls += e;
                p[r] = (short)f2bf(e);
            }
            lsum[ig] += ls;
            *(s4v*)&Ps[(ih * 32 + ig * 16 + col) * 40 + jq * 16 + quad * 4] = p;
        }
        // stage V slice (vt wait covered by QK+softmax)
        #pragma unroll
        for (int s = 0; s < 2; ++s) {
            int gi = t + 256 * s;
            int c = gi >> 2, g = gi & 3;
            int sw = (g + c + (c >> 2)) & 3;
            *(s8v*)&Vs[c * 32 + sw * 8] = vt[s];
        }
        // B3: P + V visible
        asm volatile("s_waitcnt lgkmcnt(0)" ::: "memory");
        __builtin_amdgcn_s_barrier();
        // P fragments + PV
        s8v pf[4];
        #pragma unroll
        for (int rt = 0; rt < 4; ++rt)
            pf[rt] = *(const s8v*)&Ps[(rt * 16 + col) * 40 + quad * 8];
        __builtin_amdgcn_s_setprio(1);
        #pragma unroll
        for (int ct = 0; ct < 2; ++ct) {
            int row = w * 32 + ct * 16 + col;
            int sw = (quad + row + (row >> 2)) & 3;
            s8v vf = *(const s8v*)&Vs[row * 32 + sw * 8];
            #pragma unroll
            for (int rt = 0; rt < 4; ++rt)
                accO[rt][ct] = __builtin_amdgcn_mfma_f32_16x16x32_bf16(pf[rt], vf, accO[rt][ct], 0, 0, 0);
        }
        __builtin_amdgcn_s_setprio(0);
    }

    #pragma unroll
    for (int ig = 0; ig < 2; ++ig) {
        float v = lsum[ig];
        v += __shfl_xor(v, 16);
        v += __shfl_xor(v, 32);
        if (quad == 0) lred[jq][ih * 32 + ig * 16 + col] = v;
    }
    __syncthreads();
    if (cq == 0 && t < 64)
        l_ws[((size_t)jh * B_ + b) * N_ + i0 + t] = lred[0][t] + lred[1][t];

    const size_t wbase =
        ((((size_t)jh * B_ + b) * 64 + it) * 16 + (cq * 4 + w)) * 2048;
    #pragma unroll
    for (int ct = 0; ct < 2; ++ct)
        #pragma unroll
        for (int rt = 0; rt < 4; ++rt) {
            s4v pk = { (short)f2bf(accO[rt][ct][0]), (short)f2bf(accO[rt][ct][1]),
                       (short)f2bf(accO[rt][ct][2]), (short)f2bf(accO[rt][ct][3]) };
            *(s4v*)&O_ws[wbase + (size_t)(ct * 4 + rt) * 256 + lane * 4] = pk;
        }
}

// ---------------------------------------------------------------------------
// Combine: out = gamma * (O0+O1)/(l0+l1) + x_rgb.  R13: decode updated to the
// 16-cblk O layout. Block = (b, it, cblk); thread = (rt, c_sub, qd); loop ct2.
//   O_ws[(((b*64+it)*16+cblk)*2048 + (ct2*4+rt)*256 + (qd*16+c_sub)*4 + r]
//     = O[it*64 + rt*16 + qd*4 + r][cblk*32 + ct2*16 + c_sub]
// ---------------------------------------------------------------------------
__global__ __launch_bounds__(256) void combine_kernel(
    const unsigned short* __restrict__ O_ws, const float* __restrict__ l_ws,
    const float* __restrict__ x_rgb, const float* __restrict__ gamma,
    float* __restrict__ out)
{
    const size_t half = (size_t)B_ * 64 * 16 * 2048;  // elems per j-half
    const int bx = blockIdx.x;                        // 4096 blocks
    const int cblk = bx & 15;
    const int it = (bx >> 4) & 63;
    const int b  = bx >> 10;
    const int t  = threadIdx.x;
    const int rt = t >> 6, l = t & 63;
    const int c_sub = l >> 2, qd = l & 3;

    const int i = it * 64 + rt * 16 + qd * 4;         // 4 consecutive i
    float4 l0 = *(const float4*)&l_ws[(size_t)b * N_ + i];
    float4 l1 = *(const float4*)&l_ws[(size_t)(B_ + b) * N_ + i];
    float4 linv = { 1.f / (l0.x + l1.x), 1.f / (l0.y + l1.y),
                    1.f / (l0.z + l1.z), 1.f / (l0.w + l1.w) };
    float g = gamma[0];

    #pragma unroll
    for (int ct2 = 0; ct2 < 2; ++ct2) {
        const int c = cblk * 32 + ct2 * 16 + c_sub;
        const size_t seg = (((size_t)b * 64 + it) * 16 + cblk) * 2048
                         + (size_t)(ct2 * 4 + rt) * 256 + (qd * 16 + c_sub) * 4;
        s4v o0 = *(const s4v*)&O_ws[seg];
        s4v o1 = *(const s4v*)&O_ws[half + seg];
        size_t base = ((size_t)b * C_ + c) * N_ + i;
        float4 x4 = *(const float4*)&x_rgb[base];
        float4 r;
        r.x = g * (bf2f((unsigned short)o0[0]) + bf2f((unsigned short)o1[0])) * linv.x + x4.x;
        r.y = g * (bf2f((unsigned short)o0[1]) + bf2f((unsigned short)o1[1])) * linv.y + x4.y;
        r.z = g * (bf2f((unsigned short)o0[2]) + bf2f((unsigned short)o1[2])) * linv.z + x4.z;
        r.w = g * (bf2f((unsigned short)o0[3]) + bf2f((unsigned short)o1[3])) * linv.w + x4.w;
        *(float4*)&out[base] = r;
    }
}

// ---------------------------------------------------------------------------
extern "C" void kernel_launch(void* const* d_in, const int* in_sizes, int n_in,
                              void* d_out, int out_size, void* d_ws, size_t ws_size,
                              hipStream_t stream) {
    (void)in_sizes; (void)n_in; (void)out_size; (void)ws_size;
    const float* x_rgb = (const float*)d_in[0];
    const float* x_dep = (const float*)d_in[1];
    const float* Wq    = (const float*)d_in[2];
    const float* bq    = (const float*)d_in[3];
    const float* Wk    = (const float*)d_in[4];
    const float* bk    = (const float*)d_in[5];
    const float* Wdq   = (const float*)d_in[6];
    const float* bdq   = (const float*)d_in[7];
    const float* Wdk   = (const float*)d_in[8];
    const float* bdk   = (const float*)d_in[9];
    const float* Wv    = (const float*)d_in[10];
    const float* bv    = (const float*)d_in[11];
    const float* gamma = (const float*)d_in[12];
    float* out = (float*)d_out;

    // ws (bf16 elts unless noted): Q 4MB | K 4MB | V 16.8MB | Wb 768KB |
    // biasb 4KB f32 | XtO 33.5MB (Xt during proj, O_ws during attn) |
    // l_ws 128KB f32.  Total ~59 MB.
    unsigned short* Q     = (unsigned short*)d_ws;
    unsigned short* K     = Q + (size_t)B_ * N_ * D_;
    unsigned short* V     = K + (size_t)B_ * N_ * D_;
    unsigned short* Wb    = V + (size_t)B_ * C_ * N_;
    float*          biasb = (float*)(Wb + 768 * 512);
    unsigned short* XtO   = (unsigned short*)(biasb + 1024);
    float*          l_ws  = (float*)(XtO + (size_t)2 * B_ * C_ * N_);

    cvt_w_kernel<<<dim3(192), 256, 0, stream>>>(
        Wq, bq, Wk, bk, Wdq, bdq, Wdk, bdk, Wv, bv, Wb, biasb);
    xpose_kernel<<<dim3(512, 4, 2), 256, 0, stream>>>(x_rgb, x_dep, XtO);
    gemm_kernel<<<dim3(128, 6), 256, 0, stream>>>(Wb, biasb, XtO, Q, K, V);
    attn_kernel<<<dim3(2048), 256, 0, stream>>>(Q, K, V, XtO, l_ws);
    combine_kernel<<<dim3(4096), 256, 0, stream>>>(XtO, l_ws, x_rgb, gamma, out);
}

// Round 9
// 272.802 us; speedup vs baseline: 1.2806x; 1.2806x over previous
//
#include <hip/hip_runtime.h>
#include <math.h>

#define B_ 4
#define C_ 512
#define D_ 128
#define N_ 4096

typedef short s4v __attribute__((ext_vector_type(4)));
typedef short s8v __attribute__((ext_vector_type(8)));
typedef float f4v __attribute__((ext_vector_type(4)));

__device__ __forceinline__ unsigned short f2bf(float x) {
    union { float f; unsigned u; } v; v.f = x;
    unsigned r = v.u + 0x7FFF + ((v.u >> 16) & 1);   // RNE
    return (unsigned short)(r >> 16);
}
__device__ __forceinline__ float bf2f(unsigned short h) {
    union { unsigned u; float f; } v; v.u = ((unsigned)h) << 16; return v.f;
}

// ---------------------------------------------------------------------------
// W/bias pre-convert: Wb rows [0:64]=Wq | [64:128]=Wk | [128:640]=Wv |
// [640:704]=Wdq | [704:768]=Wdk (bf16, row-major 512). biasb same order f32.
// ---------------------------------------------------------------------------
__global__ __launch_bounds__(256) void cvt_w_kernel(
    const float* __restrict__ Wq,  const float* __restrict__ bq,
    const float* __restrict__ Wk,  const float* __restrict__ bk,
    const float* __restrict__ Wdq, const float* __restrict__ bdq,
    const float* __restrict__ Wdk, const float* __restrict__ bdk,
    const float* __restrict__ Wv,  const float* __restrict__ bv,
    unsigned short* __restrict__ Wb, float* __restrict__ biasb)
{
    int t = blockIdx.x * 256 + threadIdx.x;        // 192 blocks
    int e0 = t * 8;
    int row = e0 >> 9, c = e0 & 511;
    const float* src; int r0;
    if (row < 64)       { src = Wq;  r0 = row; }
    else if (row < 128) { src = Wk;  r0 = row - 64; }
    else if (row < 640) { src = Wv;  r0 = row - 128; }
    else if (row < 704) { src = Wdq; r0 = row - 640; }
    else                { src = Wdk; r0 = row - 704; }
    const float* p = src + (size_t)r0 * 512 + c;
    s8v o;
    #pragma unroll
    for (int u = 0; u < 8; ++u) ((unsigned short*)&o)[u] = f2bf(p[u]);
    *(s8v*)&Wb[e0] = o;
    if (blockIdx.x == 0) {
        #pragma unroll
        for (int s = 0; s < 3; ++s) {
            int o2 = threadIdx.x + 256 * s;
            float v;
            if (o2 < 64)       v = bq[o2];
            else if (o2 < 128) v = bk[o2 - 64];
            else if (o2 < 640) v = bv[o2 - 128];
            else if (o2 < 704) v = bdq[o2 - 640];
            else               v = bdk[o2 - 704];
            biasb[o2] = v;
        }
    }
}

// ---------------------------------------------------------------------------
// Projection GEMM with FUSED transpose-convert (R14): xpose_kernel deleted.
// out[768 m x 16384 n] = Wb @ X^T, K=512, where X is read DIRECTLY from
// x_rgb/x_dep fp32 [b][c][i] and transpose-converted in staging:
//  * per chunk, thread (c4=t>>4, i4=t&15) loads 4c x 4i float4 blocks
//    (coalesced along i, the exact xpose pattern), f2bf in-register, writes
//    transposed s4v into Xs[128][72].  Stride-72: b64 writes 2-way conflict
//    (same as xpose paid), b128 fragment reads at the 8-access/bank floor
//    = conflict-free (addr_dw = r*36+gq*4; 8 lanes per 4-bank slot).
//  * Xs[i][c] = x[k0+c][i0+i] = Xt[i0+i][k0+c]: byte-identical B-operand.
//  * Saves: xpose launch + 67MB rd + 33.5MB wr + Xt re-read. Costs: 64 f2bf
//    VALU/thread/chunk — covered by gemm's 12 waves/SIMD TLP (R11 lesson).
// Ws path (XOR granule swizzle) and MFMA/epilogue unchanged from R12.
// LDS: Ws 16384 + Xs 18432 = 34816 B.
// ---------------------------------------------------------------------------
__global__ __launch_bounds__(256) void gemm_kernel(
    const unsigned short* __restrict__ Wb, const float* __restrict__ biasb,
    const float* __restrict__ x_rgb, const float* __restrict__ x_dep,
    unsigned short* __restrict__ Q, unsigned short* __restrict__ K,
    unsigned short* __restrict__ V)
{
    __shared__ __align__(16) unsigned short Ws[128 * 64];
    __shared__ __align__(16) unsigned short Xs[128 * 72];
    const int b  = blockIdx.x >> 5;
    const int i0 = (blockIdx.x & 31) * 128;
    const int by = blockIdx.y;
    const int mbase = by * 128;
    const int st = (by == 5);
    const int t = threadIdx.x, w = t >> 6;
    const int lane = t & 63, col = lane & 15, quad = lane >> 4;
    const int mh = (w & 1) * 64, nh = (w >> 1) * 64;
    const int c4x = t >> 4, i4x = t & 15;      // staging decode: 16c x 16i

    const unsigned short* Wg = Wb + (size_t)mbase * 512;
    const float* Xsrc = (st ? x_dep : x_rgb) + (size_t)b * C_ * N_;

    f4v acc[4][4];
    #pragma unroll
    for (int mt = 0; mt < 4; ++mt)
        #pragma unroll
        for (int nt = 0; nt < 4; ++nt) acc[mt][nt] = (f4v){0.f, 0.f, 0.f, 0.f};

    for (int kc = 0; kc < 8; ++kc) {
        const int k0 = kc * 64;
        s8v wt[4];
        float4 xr[2][4];
        #pragma unroll
        for (int s = 0; s < 4; ++s) {
            int lin = t + 256 * s;
            int row = lin >> 3, g = lin & 7;
            wt[s] = *(const s8v*)&Wg[(size_t)row * 512 + k0 + g * 8];
        }
        #pragma unroll
        for (int ih2 = 0; ih2 < 2; ++ih2) {
            const float* xp = Xsrc + (size_t)(k0 + c4x * 4) * N_
                            + i0 + ih2 * 64 + i4x * 4;
            xr[ih2][0] = *(const float4*)(xp);
            xr[ih2][1] = *(const float4*)(xp + N_);
            xr[ih2][2] = *(const float4*)(xp + 2 * N_);
            xr[ih2][3] = *(const float4*)(xp + 3 * N_);
        }
        __syncthreads();                       // prior iter's frag reads done
        #pragma unroll
        for (int s = 0; s < 4; ++s) {
            int lin = t + 256 * s;
            int row = lin >> 3, g = lin & 7;
            int soff = row * 64 + ((g ^ (row & 7)) * 8);
            *(s8v*)&Ws[soff] = wt[s];
        }
        #pragma unroll
        for (int ih2 = 0; ih2 < 2; ++ih2) {
            #pragma unroll
            for (int j = 0; j < 4; ++j) {
                s4v pj = { (short)f2bf(xr[ih2][0][j]), (short)f2bf(xr[ih2][1][j]),
                           (short)f2bf(xr[ih2][2][j]), (short)f2bf(xr[ih2][3][j]) };
                *(s4v*)&Xs[(ih2 * 64 + i4x * 4 + j) * 72 + c4x * 4] = pj;
            }
        }
        __syncthreads();                       // tile staged
        #pragma unroll
        for (int kk = 0; kk < 2; ++kk) {
            const int gq = kk * 4 + quad;
            s8v af[4], bf[4];
            #pragma unroll
            for (int mt = 0; mt < 4; ++mt) {
                int r = mh + mt * 16 + col;
                af[mt] = *(const s8v*)&Ws[r * 64 + ((gq ^ (r & 7)) * 8)];
            }
            #pragma unroll
            for (int nt = 0; nt < 4; ++nt) {
                int r = nh + nt * 16 + col;
                bf[nt] = *(const s8v*)&Xs[r * 72 + gq * 8];
            }
            #pragma unroll
            for (int nt = 0; nt < 4; ++nt)
                #pragma unroll
                for (int mt = 0; mt < 4; ++mt)
                    acc[mt][nt] = __builtin_amdgcn_mfma_f32_16x16x32_bf16(
                        af[mt], bf[nt], acc[mt][nt], 0, 0, 0);
        }
    }

    // ---- epilogue ----
    const int mlo0 = mbase + mh;               // wave-uniform
    #pragma unroll
    for (int mt = 0; mt < 4; ++mt) {
        const int mlo = mlo0 + mt * 16;
        f4v bi = *(const f4v*)&biasb[mlo + quad * 4];
        if (mlo < 128 || mlo >= 640) {         // Q/K rows
            unsigned short* dst; int dbase;
            if (mlo < 64)       { dst = Q; dbase = mlo; }
            else if (mlo < 128) { dst = K; dbase = mlo - 64; }
            else if (mlo < 704) { dst = Q; dbase = 64 + (mlo - 640); }
            else                { dst = K; dbase = 64 + (mlo - 704); }
            #pragma unroll
            for (int nt = 0; nt < 4; ++nt) {
                int i = i0 + nh + nt * 16 + col;
                s4v pk = { (short)f2bf(acc[mt][nt][0] + bi[0]),
                           (short)f2bf(acc[mt][nt][1] + bi[1]),
                           (short)f2bf(acc[mt][nt][2] + bi[2]),
                           (short)f2bf(acc[mt][nt][3] + bi[3]) };
                *(s4v*)&dst[((size_t)b * N_ + i) * D_ + dbase + quad * 4] = pk;
            }
        } else {                               // V rows
            int c0 = mlo - 128 + quad * 4;
            #pragma unroll
            for (int nt = 0; nt < 4; ++nt) {
                int i = i0 + nh + nt * 16 + col;
                #pragma unroll
                for (int r = 0; r < 4; ++r)
                    V[((size_t)b * C_ + c0 + r) * N_ + i] =
                        f2bf(acc[mt][nt][r] + bi[r]);
            }
        }
    }
}

// ---------------------------------------------------------------------------
// MFMA flash attention — byte-exact R12 structure (best measured: ~118us).
// R13's c-split-4 was refuted: occupancy doubled but chip-wide MFMA work
// rose 1.6x (QK/softmax duplication) and dur scaled with work. FROZEN.
//  * XCD group swizzle (FETCH 84->14MB), flat grid 512, id&7 = (b,jh).
//  * lgkm-only barriers; no vmcnt(0) drain; kt oldest-first; Vs write after
//    QK+softmax; T5 setprio around PV cluster.
// LDS: Ks 8704 | Ps 5120 | Vs 32768 | lred 512 = 47104 B -> 2 blocks/CU.
// ---------------------------------------------------------------------------
__global__ __launch_bounds__(256, 2) void attn_kernel(
    const unsigned short* __restrict__ Q, const unsigned short* __restrict__ K,
    const unsigned short* __restrict__ V,
    unsigned short* __restrict__ O_ws, float* __restrict__ l_ws)
{
    __shared__ __align__(16) unsigned short Ks[32 * 136];
    __shared__ __align__(16) unsigned short Ps[64 * 40];
    __shared__ __align__(16) unsigned short Vs[512 * 32];
    __shared__ float lred[2][64];

    const int id  = blockIdx.x;
    const int grp = id & 7;                 // XCD-affine group
    const int b   = grp & 3;
    const int jh  = grp >> 2;
    const int it  = id >> 3;                // i-tile 0..63
    const int i0  = it * 64;
    const int jb  = jh * 2048;
    const int t = threadIdx.x, w = t >> 6;
    const int lane = t & 63, col = lane & 15, quad = lane >> 4;
    const int ih = w & 1, jq = w >> 1;

    const unsigned short* Kg = K + (size_t)b * N_ * D_;
    const unsigned short* Vg = V + (size_t)b * C_ * N_;

    s8v qf[2][4];
    #pragma unroll
    for (int ig = 0; ig < 2; ++ig) {
        const unsigned short* qr =
            Q + ((size_t)b * N_ + i0 + ih * 32 + ig * 16 + col) * D_ + quad * 8;
        #pragma unroll
        for (int kk = 0; kk < 4; ++kk) qf[ig][kk] = *(const s8v*)(qr + kk * 32);
    }

    f4v accO[4][8];
    #pragma unroll
    for (int rt = 0; rt < 4; ++rt)
        #pragma unroll
        for (int ct = 0; ct < 8; ++ct) accO[rt][ct] = (f4v){0.f, 0.f, 0.f, 0.f};
    float lsum[2] = {0.f, 0.f};

    for (int tt = 0; tt < 64; ++tt) {
        const int j0 = jb + tt * 32;
        // issue loads: kt FIRST (oldest -> Ks write waits vmcnt(8) = kt only)
        s8v kt[2], vt[8];
        #pragma unroll
        for (int s = 0; s < 2; ++s) {
            int gi = t + 256 * s;
            kt[s] = *(const s8v*)&Kg[(size_t)(j0 + (gi >> 4)) * D_ + (gi & 15) * 8];
        }
        #pragma unroll
        for (int s = 0; s < 8; ++s) {
            int gi = t + 256 * s;
            vt[s] = *(const s8v*)&Vg[(size_t)(gi >> 2) * N_ + j0 + (gi & 3) * 8];
        }
        // B1: prior iter's Vs/Ps reads (and Ks reads) complete
        asm volatile("s_waitcnt lgkmcnt(0)" ::: "memory");
        __builtin_amdgcn_s_barrier();
        // stage K tile (vmcnt(8): waits kt, vt stays in flight)
        #pragma unroll
        for (int s = 0; s < 2; ++s) {
            int gi = t + 256 * s;
            *(s8v*)&Ks[(gi >> 4) * 136 + (gi & 15) * 8] = kt[s];
        }
        // B2: K tile staged
        asm volatile("s_waitcnt lgkmcnt(0)" ::: "memory");
        __builtin_amdgcn_s_barrier();
        // QK^T
        f4v s0 = (f4v){0.f, 0.f, 0.f, 0.f};
        f4v s1 = (f4v){0.f, 0.f, 0.f, 0.f};
        #pragma unroll
        for (int kk = 0; kk < 4; ++kk) {
            s8v kf = *(const s8v*)&Ks[(jq * 16 + col) * 136 + kk * 32 + quad * 8];
            s0 = __builtin_amdgcn_mfma_f32_16x16x32_bf16(kf, qf[0][kk], s0, 0, 0, 0);
            s1 = __builtin_amdgcn_mfma_f32_16x16x32_bf16(kf, qf[1][kk], s1, 0, 0, 0);
        }
        // softmax partials + pack P
        #pragma unroll
        for (int ig = 0; ig < 2; ++ig) {
            f4v sv = ig ? s1 : s0;
            s4v p; float ls = 0.f;
            #pragma unroll
            for (int r = 0; r < 4; ++r) {
                float e = __expf(sv[r]);
                ls += e;
                p[r] = (short)f2bf(e);
            }
            lsum[ig] += ls;
            *(s4v*)&Ps[(ih * 32 + ig * 16 + col) * 40 + jq * 16 + quad * 4] = p;
        }
        // stage V tile (vmcnt wait for vt covered by QK+softmax above)
        #pragma unroll
        for (int s = 0; s < 8; ++s) {
            int gi = t + 256 * s;
            int c = gi >> 2, g = gi & 3;
            int sw = (g + c + (c >> 2)) & 3;
            *(s8v*)&Vs[c * 32 + sw * 8] = vt[s];
        }
        // B3: P + V visible
        asm volatile("s_waitcnt lgkmcnt(0)" ::: "memory");
        __builtin_amdgcn_s_barrier();
        // P fragments + PV
        s8v pf[4];
        #pragma unroll
        for (int rt = 0; rt < 4; ++rt)
            pf[rt] = *(const s8v*)&Ps[(rt * 16 + col) * 40 + quad * 8];
        __builtin_amdgcn_s_setprio(1);
        #pragma unroll
        for (int ct = 0; ct < 8; ++ct) {
            int row = w * 128 + ct * 16 + col;
            int sw = (quad + row + (row >> 2)) & 3;
            s8v vf = *(const s8v*)&Vs[row * 32 + sw * 8];
            #pragma unroll
            for (int rt = 0; rt < 4; ++rt)
                accO[rt][ct] = __builtin_amdgcn_mfma_f32_16x16x32_bf16(pf[rt], vf, accO[rt][ct], 0, 0, 0);
        }
        __builtin_amdgcn_s_setprio(0);
    }

    #pragma unroll
    for (int ig = 0; ig < 2; ++ig) {
        float v = lsum[ig];
        v += __shfl_xor(v, 16);
        v += __shfl_xor(v, 32);
        if (quad == 0) lred[jq][ih * 32 + ig * 16 + col] = v;
    }
    __syncthreads();
    if (t < 64)
        l_ws[((size_t)jh * B_ + b) * N_ + i0 + t] = lred[0][t] + lred[1][t];

    const size_t wbase =
        ((((size_t)jh * B_ + b) * 64 + it) * 4 + w) * 8192;
    #pragma unroll
    for (int ct = 0; ct < 8; ++ct)
        #pragma unroll
        for (int rt = 0; rt < 4; ++rt) {
            s4v pk = { (short)f2bf(accO[rt][ct][0]), (short)f2bf(accO[rt][ct][1]),
                       (short)f2bf(accO[rt][ct][2]), (short)f2bf(accO[rt][ct][3]) };
            *(s4v*)&O_ws[wbase + (size_t)(ct * 4 + rt) * 256 + lane * 4] = pk;
        }
}

// ---------------------------------------------------------------------------
// Combine: out = gamma * (O0+O1)/(l0+l1) + x_rgb.  (Byte-exact R12 version:
// dense-read mapping, 2 ct-segments per thread, grid 4096.)
//   O_ws[wbase(jh,b,it,w) + (ct*4+rt)*256 + (qd*16+col)*4 + r]
//     = O[it*64 + rt*16 + qd*4 + r][w*128 + ct*16 + col]
// ---------------------------------------------------------------------------
__global__ __launch_bounds__(256) void combine_kernel(
    const unsigned short* __restrict__ O_ws, const float* __restrict__ l_ws,
    const float* __restrict__ x_rgb, const float* __restrict__ gamma,
    float* __restrict__ out)
{
    const size_t half = (size_t)B_ * 64 * 4 * 8192;   // elems per j-half
    const int bx = blockIdx.x;                        // 4096 blocks
    const int ct0 = (bx & 3) * 2;                     // 2 ct per block
    const int w  = (bx >> 2) & 3;
    const int it = (bx >> 4) & 63;
    const int b  = bx >> 10;
    const int t  = threadIdx.x;
    const int rt = t >> 6, l = t & 63;
    const int c_sub = l >> 2, qd = l & 3;

    const int i = it * 64 + rt * 16 + qd * 4;         // 4 consecutive i
    float4 l0 = *(const float4*)&l_ws[(size_t)b * N_ + i];
    float4 l1 = *(const float4*)&l_ws[(size_t)(B_ + b) * N_ + i];
    float4 linv = { 1.f / (l0.x + l1.x), 1.f / (l0.y + l1.y),
                    1.f / (l0.z + l1.z), 1.f / (l0.w + l1.w) };
    float g = gamma[0];

    #pragma unroll
    for (int u = 0; u < 2; ++u) {
        const int ct = ct0 + u;
        const int c = w * 128 + ct * 16 + c_sub;
        const size_t seg = (((size_t)b * 64 + it) * 4 + w) * 8192
                         + (size_t)(ct * 4 + rt) * 256 + (qd * 16 + c_sub) * 4;
        s4v o0 = *(const s4v*)&O_ws[seg];
        s4v o1 = *(const s4v*)&O_ws[half + seg];
        size_t base = ((size_t)b * C_ + c) * N_ + i;
        float4 x4 = *(const float4*)&x_rgb[base];
        float4 r;
        r.x = g * (bf2f((unsigned short)o0[0]) + bf2f((unsigned short)o1[0])) * linv.x + x4.x;
        r.y = g * (bf2f((unsigned short)o0[1]) + bf2f((unsigned short)o1[1])) * linv.y + x4.y;
        r.z = g * (bf2f((unsigned short)o0[2]) + bf2f((unsigned short)o1[2])) * linv.z + x4.z;
        r.w = g * (bf2f((unsigned short)o0[3]) + bf2f((unsigned short)o1[3])) * linv.w + x4.w;
        *(float4*)&out[base] = r;
    }
}

// ---------------------------------------------------------------------------
extern "C" void kernel_launch(void* const* d_in, const int* in_sizes, int n_in,
                              void* d_out, int out_size, void* d_ws, size_t ws_size,
                              hipStream_t stream) {
    (void)in_sizes; (void)n_in; (void)out_size; (void)ws_size;
    const float* x_rgb = (const float*)d_in[0];
    const float* x_dep = (const float*)d_in[1];
    const float* Wq    = (const float*)d_in[2];
    const float* bq    = (const float*)d_in[3];
    const float* Wk    = (const float*)d_in[4];
    const float* bk    = (const float*)d_in[5];
    const float* Wdq   = (const float*)d_in[6];
    const float* bdq   = (const float*)d_in[7];
    const float* Wdk   = (const float*)d_in[8];
    const float* bdk   = (const float*)d_in[9];
    const float* Wv    = (const float*)d_in[10];
    const float* bv    = (const float*)d_in[11];
    const float* gamma = (const float*)d_in[12];
    float* out = (float*)d_out;

    // ws (bf16 elts unless noted): Q 4MB | K 4MB | V 16.8MB | Wb 768KB |
    // biasb 4KB f32 | O_ws 33.5MB | l_ws 128KB f32.  (Xt eliminated in R14 —
    // gemm reads x directly; O_ws region reused name XtO for layout compat.)
    unsigned short* Q     = (unsigned short*)d_ws;
    unsigned short* K     = Q + (size_t)B_ * N_ * D_;
    unsigned short* V     = K + (size_t)B_ * N_ * D_;
    unsigned short* Wb    = V + (size_t)B_ * C_ * N_;
    float*          biasb = (float*)(Wb + 768 * 512);
    unsigned short* XtO   = (unsigned short*)(biasb + 1024);
    float*          l_ws  = (float*)(XtO + (size_t)2 * B_ * C_ * N_);

    cvt_w_kernel<<<dim3(192), 256, 0, stream>>>(
        Wq, bq, Wk, bk, Wdq, bdq, Wdk, bdk, Wv, bv, Wb, biasb);
    gemm_kernel<<<dim3(128, 6), 256, 0, stream>>>(Wb, biasb, x_rgb, x_dep, Q, K, V);
    attn_kernel<<<dim3(512), 256, 0, stream>>>(Q, K, V, XtO, l_ws);
    combine_kernel<<<dim3(4096), 256, 0, stream>>>(XtO, l_ws, x_rgb, gamma, out);
}